// Round 10
// baseline (160.796 us; speedup 1.0000x reference)
//
#include <hip/hip_runtime.h>
#include <math.h>

namespace {

constexpr int kT = 365;
constexpr int kG = 2000;
constexpr int kM = 8;     // ensemble multiplier
constexpr int kF = 15;    // UH length
constexpr float kPrecs = 1e-5f;

typedef __attribute__((ext_vector_type(2))) float f32x2;

// ws float offsets: [0, kF*kG) zero pad | q[T][G] | w[15][G]
constexpr int kQBase = kF * kG;
constexpr int kWBase = (kF + kT) * kG;

__device__ __forceinline__ float rcpf(float v) { return __builtin_amdgcn_rcpf(v); }
__device__ __forceinline__ float clampf(float x, float lo, float hi) {
    return __builtin_amdgcn_fmed3f(x, lo, hi);   // v_med3_f32 clamp idiom (lo<=hi, no NaN)
}

// v += quad_perm-permuted v via DPP (pure VALU, no LDS pipe)
template <int CTRL>
__device__ __forceinline__ float dpp_xadd(float v) {
    int r = __builtin_amdgcn_update_dpp(0, __float_as_int(v), CTRL, 0xF, 0xF, true);
    return v + __int_as_float(r);
}

// param-only derived quantities (computed one pipeline stage ahead); 2 rcp + 1 log2
struct Derived {
    float pctim, kuz, pfree;
    float uztwm, uzfwm, lztwm;
    f32x2 Mlz;                       // (lzfwpm, lzfwsm)
    f32x2 Klz;                       // (klzp, klzs)
    float r_uztwm, r_uzfwm, r_lztwm, r_uzsum;
    float pbase, Zp, rexp1, c_pow;   // demand = pbase + Zp*powv; powv=exp2(rexp1*log2(def)-c_pow)
    float s23m, r_den, flz_fb;
};

__device__ __forceinline__ Derived make_derived(const float pr[11]) {
#pragma clang fp contract(fast)
    Derived d;
    d.pctim = pr[0];
    const float smax = pr[1] * 1999.f + 1.f;
    const float f1   = pr[2] * 0.99f + 0.005f;
    const float f2   = pr[3] * 0.99f + 0.005f;
    d.kuz            = pr[4];
    const float rexp = pr[5] * 7.f;
    const float f3   = pr[6] * 0.99f + 0.005f;
    const float f4   = pr[7] * 0.99f + 0.005f;
    d.pfree = pr[8];
    const float klzp = pr[9], klzs = pr[10];

    d.uztwm  = fmaxf(kPrecs, f1 * smax);
    d.uzfwm  = fmaxf(kPrecs, f2 * (smax - d.uztwm));
    d.lztwm  = fmaxf(kPrecs, f3 * (smax - d.uztwm - d.uzfwm));
    const float rem = smax - d.uztwm - d.uzfwm - d.lztwm;
    const float lzfwpm = fmaxf(kPrecs, f4 * rem);
    const float lzfwsm = fmaxf(kPrecs, (1.f - f4) * rem);
    d.Mlz = (f32x2){lzfwpm, lzfwsm};
    d.Klz = (f32x2){klzp, klzs};

    const float totalm = d.lztwm + lzfwpm + lzfwsm;
    d.pbase  = lzfwpm * klzp + lzfwsm * klzs;
    d.Zp     = totalm - d.pbase;          // == pbase*zperc (exact algebraic identity)
    d.rexp1  = 1.f + rexp;
    d.c_pow  = d.rexp1 * __log2f(totalm);

    // combined reciprocals (1 rcp each zone): R=rcp(a*b*s) -> rcp(a)=b*s*R, ...
    {   // upper zone: a=uztwm, b=uzfwm, s=a+b
        const float s  = d.uztwm + d.uzfwm;
        const float ab = d.uztwm * d.uzfwm;
        const float R  = rcpf(ab * s);
        const float sR = s * R;
        d.r_uztwm = d.uzfwm * sR;
        d.r_uzfwm = d.uztwm * sR;
        d.r_uzsum = ab * R;
    }
    d.s23m = lzfwpm + lzfwsm;
    {   // lower zone: u=lztwm, v=s23m, den=v*totalm
        const float den = d.s23m * totalm;
        const float uv  = d.lztwm * d.s23m;
        const float R2  = rcpf(uv * den);
        d.r_lztwm = d.s23m * (den * R2);
        d.r_den   = uv * R2;
        d.flz_fb  = lzfwpm * (d.lztwm * (den * R2));   // lzfwpm * rcp(s23m)
    }
    return d;
}

struct PBuf { float pr[11]; float P, Ep; };

// ---------------- kernel A: the sequential scan ----------------
__global__ __launch_bounds__(64, 1) void sacsma_scan(
    const float* __restrict__ x,           // [T, G, 4]
    const float* __restrict__ params_raw,  // [T, G, 11, M]
    float* __restrict__ qs)                // ws q region: [T][G] (sum over m)
{
#pragma clang fp contract(fast)
#pragma clang fp reassociate(on)
    const int tid = blockIdx.x * 64 + threadIdx.x;
    const int g = tid >> 3;
    const int m = tid & 7;

    const size_t PS = (size_t)kG * 11 * kM;  // param stride per t (floats)
    const float* pp = params_raw + (size_t)g * 88 + m;
    const float4* xp4 = (const float4*)x + g;   // index by t*kG

    float uztw = 1e-4f, uzfw = 1e-4f, lztw = 1e-4f;
    f32x2 lz = {1e-4f, 1e-4f};              // (lzfwp, lzfws), packed

    PBuf A, B, C, D;

#define ISSUE(BUF, T3) do {                                              \
        const size_t _po = (size_t)(T3) * PS;                            \
        _Pragma("unroll")                                                \
        for (int _i = 0; _i < 11; ++_i) BUF.pr[_i] = pp[_po + _i * kM];  \
        const float4 _xv = xp4[(size_t)(T3) * kG];                       \
        BUF.P = _xv.x; BUF.Ep = _xv.w;                                   \
    } while (0)

    // prologue: t=0 params -> d0; prefetch t=1..4 into A..D (distance-4 pipeline)
    float pr0[11];
#pragma unroll
    for (int i = 0; i < 11; ++i) pr0[i] = pp[i * kM];
    const float4 xv0 = xp4[0];
    ISSUE(A, 1);
    ISSUE(B, 2);
    ISSUE(C, 3);
    ISSUE(D, 4);
    Derived d0 = make_derived(pr0);
    Derived d1;
    float P = xv0.x, Ep = xv0.w;

    float q0 = 0.f, q1 = 0.f, q2 = 0.f, q3 = 0.f;

#define FLUX(DD, QREG) do {                                                   \
        const float qdir = DD.pctim * P;                                      \
        const float peff = P - qdir;                                          \
        const float ratio_u1 = uztw * DD.r_uztwm;                             \
        const float ratio_u2 = uzfw * DD.r_uzfwm;                             \
        const float ru = (ratio_u1 < ratio_u2)                                \
            ? (uzfw * DD.uztwm - uztw * DD.uzfwm) * DD.r_uzsum : 0.f;         \
        const float euztw = fminf(ratio_u1 * Ep, uztw);                       \
        const float twexu = (uztw >= DD.uztwm) ? peff : 0.f;                  \
        const float qsur  = (uzfw >= DD.uzfwm) ? twexu : 0.f;                 \
        const float qint  = DD.kuz * uzfw;                                    \
        const float erem  = fmaxf(Ep - euztw, 0.f);                           \
        const float euzfw = fminf(uzfw, erem);                                \
        const f32x2 dP    = DD.Mlz - lz;          /* >=0 by clip (pk_sub) */  \
        const float deficit = fmaxf(DD.lztwm - lztw, 0.f)                     \
                            + fmaxf(dP.x, 0.f) + fmaxf(dP.y, 0.f);            \
        const float powv = exp2f(DD.rexp1 * __log2f(deficit) - DD.c_pow);     \
        const float demand = DD.pbase + DD.Zp * powv;                         \
        const float srel = fmaxf(1e-8f, ratio_u2);                            \
        const float pc   = fmaxf(1e-8f, fminf(uzfw, srel * demand));          \
        const float pcfw = DD.pfree * pc;                                     \
        const float pctw = pc - pcfw;                                         \
        const f32x2 Msw = __builtin_shufflevector(DD.Mlz, DD.Mlz, 1, 0);      \
        const f32x2 nn  = dP * Msw;               /* (n1,n2) pk_mul */        \
        const float ns  = nn.x + nn.y;                                        \
        const float flz = (ns != 0.f) ? nn.x * rcpf(ns) : DD.flz_fb;          \
        const f32x2 flzP  = {flz, 1.f - flz};                                 \
        const f32x2 pcfwP = flzP * pcfw;          /* pk_mul (splat) */        \
        const f32x2 qbf   = DD.Klz * lz;          /* (qbfp,qbfs) pk_mul */    \
        const float lsum  = lz.x + lz.y;                                      \
        const float ratio_l = lztw * DD.r_lztwm;                              \
        const bool  lmask = lztw * DD.s23m < lsum * DD.lztwm;                 \
        const float nume = (lztw * DD.s23m + DD.lztwm * lsum) * DD.r_den;     \
        const f32x2 rlP = lmask ? lz * nume : (f32x2){0.f, 0.f};              \
        const float elztw = fminf(ratio_l * fmaxf(erem - euzfw, 0.f), lztw);  \
        const float twexl = (lztw >= DD.lztwm) ? pctw : 0.f;                  \
        const f32x2 twexlP = flzP * twexl;        /* pk_mul (splat) */        \
        QREG = qdir + qsur + qint + qbf.x + qbf.y;                            \
        uztw = clampf(uztw + peff + ru - euztw - twexu, kPrecs, DD.uztwm);    \
        uzfw = clampf(uzfw + twexu - ru - euzfw - qint - qsur - pc,           \
                      kPrecs, DD.uzfwm);                                      \
        lztw = clampf(lztw + pctw - twexl + rlP.x + rlP.y - elztw,            \
                      kPrecs, DD.lztwm);                                      \
        const f32x2 lzn = lz + pcfwP + twexlP - rlP - qbf;  /* pk chain */    \
        lz.x = clampf(lzn.x, kPrecs, DD.Mlz.x);                               \
        lz.y = clampf(lzn.y, kPrecs, DD.Mlz.y);                               \
    } while (0)

    // body: FLUX with DCUR, build DNXT from BUF (t+1 params), rotate P/Ep, reissue BUF <- t+5
#define BODY(T, DCUR, DNXT, BUF, QREG) do {                                   \
        FLUX(DCUR, QREG);                                                     \
        DNXT = make_derived(BUF.pr);                                          \
        P = BUF.P; Ep = BUF.Ep;                                               \
        ISSUE(BUF, (T) + 5);   /* main loop: (T)+5 <= 364 always valid */     \
    } while (0)

    // tail body: no reissue
#define BODY_NR(DCUR, DNXT, BUF, QREG) do {                                   \
        FLUX(DCUR, QREG);                                                     \
        DNXT = make_derived(BUF.pr);                                          \
        P = BUF.P; Ep = BUF.Ep;                                               \
    } while (0)

    // batched m-reduction + store of 4 steps: xor1/xor2 via DPP, xor4 via swizzle
#define FLUSH(TB) do {                                                        \
        q0 = dpp_xadd<0xB1>(q0); q1 = dpp_xadd<0xB1>(q1);                     \
        q2 = dpp_xadd<0xB1>(q2); q3 = dpp_xadd<0xB1>(q3);                     \
        q0 = dpp_xadd<0x4E>(q0); q1 = dpp_xadd<0x4E>(q1);                     \
        q2 = dpp_xadd<0x4E>(q2); q3 = dpp_xadd<0x4E>(q3);                     \
        q0 += __shfl_xor(q0, 4); q1 += __shfl_xor(q1, 4);                     \
        q2 += __shfl_xor(q2, 4); q3 += __shfl_xor(q3, 4);                     \
        const float _v01 = (m & 1) ? q1 : q0;                                 \
        const float _v23 = (m & 1) ? q3 : q2;                                 \
        const float _v = (m & 2) ? _v23 : _v01;                               \
        if (m < 4) qs[(size_t)((TB) + m) * kG + g] = _v;                      \
    } while (0)

    for (int t = 0; t < 360; t += 4) {   // bodies 0..359; reissues reach t=364 max
        BODY(t,     d0, d1, A, q0);
        BODY(t + 1, d1, d0, B, q1);
        BODY(t + 2, d0, d1, C, q2);
        BODY(t + 3, d1, d0, D, q3);
        FLUSH(t);
    }
    // tail: bodies 360..364; buffers hold A:361 B:362 C:363 D:364
    BODY_NR(d0, d1, A, q0);
    BODY_NR(d1, d0, B, q1);
    BODY_NR(d0, d1, C, q2);
    BODY_NR(d1, d0, D, q3);
    FLUSH(360);
    FLUX(d0, q0);   // t=364 (even -> d0)
    q0 = dpp_xadd<0xB1>(q0);
    q0 = dpp_xadd<0x4E>(q0);
    q0 += __shfl_xor(q0, 4);
    if (m == 0) qs[(size_t)364 * kG + g] = q0;

#undef FLUX
#undef BODY
#undef BODY_NR
#undef ISSUE
#undef FLUSH
}

// ---------------- kernel B: gamma UH weights + pad zeroing (fused) ----------------
__global__ void uh_weights(const float* __restrict__ conv_params,
                           float* __restrict__ ws)   // scratch base
{
    const int idx = blockIdx.x * blockDim.x + threadIdx.x;
    if (idx < kQBase) ws[idx] = 0.f;          // zero the t<0 conv pad (every call)
    const int g = idx;
    if (g >= kG) return;
    float* wbuf = ws + kWBase;
    const float aa = fmaxf(conv_params[2 * g] * 2.9f, 0.f) + 0.1f;
    const float th = fmaxf(conv_params[2 * g + 1] * 6.5f, 0.f) + 0.5f;
    const float cw = expf(-lgammaf(aa)) * powf(th, -aa);
    float w[kF];
    float s = 0.f;
#pragma unroll
    for (int k = 0; k < kF; ++k) {
        const float tt = (float)k + 0.5f;
        w[k] = cw * powf(tt, aa - 1.f) * expf(-tt / th);
        s += w[k];
    }
    const float inv = 0.125f / s;   // normalize + fold ensemble mean (q stored as sum)
#pragma unroll
    for (int k = 0; k < kF; ++k) wbuf[k * kG + g] = w[k] * inv;
}

// ---------------- kernel C: causal UH convolution ----------------
__global__ void uh_conv(const float* __restrict__ ws,   // base of scratch
                        float* __restrict__ out)        // [T][G]
{
    const int tid = blockIdx.x * blockDim.x + threadIdx.x;
    if (tid >= kT * kG) return;
    const int t = tid / kG;
    const int g = tid - t * kG;
    const float* q = ws + kQBase;   // q[t] at q[t*kG+g]; t<0 hits the zero pad
    const float* w = ws + kWBase;
    float y = 0.f;
#pragma unroll
    for (int k = 0; k < kF; ++k)
        y += w[k * kG + g] * q[(ptrdiff_t)(t - k) * kG + g];
    out[(size_t)t * kG + g] = y;
}

}  // namespace

extern "C" void kernel_launch(void* const* d_in, const int* in_sizes, int n_in,
                              void* d_out, int out_size, void* d_ws, size_t ws_size,
                              hipStream_t stream) {
    const float* x           = (const float*)d_in[0];
    // d_in[1] = c_hydro_model — unused by the reference forward
    const float* params_raw  = (const float*)d_in[2];
    const float* conv_params = (const float*)d_in[3];
    float* out = (float*)d_out;
    float* ws  = (float*)d_ws;

    // fused: zero conv pad + compute UH weights (covers kQBase=30000 threads)
    uh_weights<<<(kQBase + 255) / 256, 256, 0, stream>>>(conv_params, ws);
    sacsma_scan<<<(kG * kM) / 64, 64, 0, stream>>>(x, params_raw, ws + kQBase);
    uh_conv<<<(kT * kG + 255) / 256, 256, 0, stream>>>(ws, out);
}

// Round 11
// 147.831 us; speedup vs baseline: 1.0877x; 1.0877x over previous
//
#include <hip/hip_runtime.h>
#include <math.h>

namespace {

constexpr int kT = 365;
constexpr int kG = 2000;
constexpr int kM = 8;     // ensemble multiplier
constexpr int kF = 15;    // UH length
constexpr float kPrecs = 1e-5f;

// ws float offsets: [0, kF*kG) zero pad | q[T][G] | w[15][G]
constexpr int kQBase = kF * kG;
constexpr int kWBase = (kF + kT) * kG;

__device__ __forceinline__ float rcpf(float v) { return __builtin_amdgcn_rcpf(v); }
__device__ __forceinline__ float clampf(float x, float lo, float hi) {
    return __builtin_amdgcn_fmed3f(x, lo, hi);   // v_med3_f32 clamp idiom (finite, lo<=hi)
}

// v += quad_perm-permuted v via DPP (pure VALU, no LDS pipe)
template <int CTRL>
__device__ __forceinline__ float dpp_xadd(float v) {
    int r = __builtin_amdgcn_update_dpp(0, __float_as_int(v), CTRL, 0xF, 0xF, true);
    return v + __int_as_float(r);
}

// param-only derived quantities (computed one pipeline stage ahead); 2 rcp + 1 log2
struct Derived {
    float pctim, kuz, pfree, klzp, klzs;
    float uztwm, uzfwm, lztwm, lzfwpm, lzfwsm;
    float r_uztwm, r_uzfwm, r_lztwm, r_uzsum;
    float pbase, Zp, rexp1, c_pow;   // demand = pbase + Zp*powv; powv=exp2(rexp1*log2(def)-c_pow)
    float s23m, r_den, flz_fb;
};

__device__ __forceinline__ Derived make_derived(const float pr[11]) {
#pragma clang fp contract(fast)
    Derived d;
    d.pctim = pr[0];
    const float smax = pr[1] * 1999.f + 1.f;
    const float f1   = pr[2] * 0.99f + 0.005f;
    const float f2   = pr[3] * 0.99f + 0.005f;
    d.kuz            = pr[4];
    const float rexp = pr[5] * 7.f;
    const float f3   = pr[6] * 0.99f + 0.005f;
    const float f4   = pr[7] * 0.99f + 0.005f;
    d.pfree = pr[8]; d.klzp = pr[9]; d.klzs = pr[10];

    d.uztwm  = fmaxf(kPrecs, f1 * smax);
    d.uzfwm  = fmaxf(kPrecs, f2 * (smax - d.uztwm));
    d.lztwm  = fmaxf(kPrecs, f3 * (smax - d.uztwm - d.uzfwm));
    const float rem = smax - d.uztwm - d.uzfwm - d.lztwm;
    d.lzfwpm = fmaxf(kPrecs, f4 * rem);
    d.lzfwsm = fmaxf(kPrecs, (1.f - f4) * rem);

    const float totalm = d.lztwm + d.lzfwpm + d.lzfwsm;
    d.pbase  = d.lzfwpm * d.klzp + d.lzfwsm * d.klzs;
    d.Zp     = totalm - d.pbase;          // == pbase*zperc (exact algebraic identity)
    d.rexp1  = 1.f + rexp;
    d.c_pow  = d.rexp1 * __log2f(totalm);

    // combined reciprocals (1 rcp each zone): R=rcp(a*b*s) -> rcp(a)=b*s*R, ...
    {   // upper zone: a=uztwm, b=uzfwm, s=a+b
        const float s  = d.uztwm + d.uzfwm;
        const float ab = d.uztwm * d.uzfwm;
        const float R  = rcpf(ab * s);
        const float sR = s * R;
        d.r_uztwm = d.uzfwm * sR;
        d.r_uzfwm = d.uztwm * sR;
        d.r_uzsum = ab * R;
    }
    d.s23m = d.lzfwpm + d.lzfwsm;
    {   // lower zone: u=lztwm, v=s23m, den=v*totalm
        const float den = d.s23m * totalm;
        const float uv  = d.lztwm * d.s23m;
        const float R2  = rcpf(uv * den);
        d.r_lztwm = d.s23m * (den * R2);
        d.r_den   = uv * R2;
        d.flz_fb  = d.lzfwpm * (d.lztwm * (den * R2));   // lzfwpm * rcp(s23m)
    }
    return d;
}

struct PBuf { float pr[11]; float P, Ep; };

// ---------------- kernel A: the sequential scan ----------------
__global__ __launch_bounds__(64, 1) void sacsma_scan(
    const float* __restrict__ x,           // [T, G, 4]
    const float* __restrict__ params_raw,  // [T, G, 11, M]
    float* __restrict__ qs)                // ws q region: [T][G] (sum over m)
{
#pragma clang fp contract(fast)
#pragma clang fp reassociate(on)
    const int tid = blockIdx.x * 64 + threadIdx.x;
    const int g = tid >> 3;
    const int m = tid & 7;

    const size_t PS = (size_t)kG * 11 * kM;  // param stride per t (floats)
    const float* pp = params_raw + (size_t)g * 88 + m;
    const float4* xp4 = (const float4*)x + g;   // index by t*kG

    float uztw = 1e-4f, uzfw = 1e-4f, lztw = 1e-4f, lzfwp = 1e-4f, lzfws = 1e-4f;

    PBuf A, B, C, D;

#define ISSUE(BUF, T3) do {                                              \
        const size_t _po = (size_t)(T3) * PS;                            \
        _Pragma("unroll")                                                \
        for (int _i = 0; _i < 11; ++_i) BUF.pr[_i] = pp[_po + _i * kM];  \
        const float4 _xv = xp4[(size_t)(T3) * kG];                       \
        BUF.P = _xv.x; BUF.Ep = _xv.w;                                   \
    } while (0)

    // prologue: t=0 params -> d0; prefetch t=1..4 into A..D (distance-4 pipeline)
    float pr0[11];
#pragma unroll
    for (int i = 0; i < 11; ++i) pr0[i] = pp[i * kM];
    const float4 xv0 = xp4[0];
    ISSUE(A, 1);
    ISSUE(B, 2);
    ISSUE(C, 3);
    ISSUE(D, 4);
    Derived d0 = make_derived(pr0);
    Derived d1;
    float P = xv0.x, Ep = xv0.w;

    float q0 = 0.f, q1 = 0.f, q2 = 0.f, q3 = 0.f;

#define FLUX(DD, QREG) do {                                                   \
        const float qdir = DD.pctim * P;                                      \
        const float peff = P - qdir;                                          \
        const float ratio_u1 = uztw * DD.r_uztwm;                             \
        const float ratio_u2 = uzfw * DD.r_uzfwm;                             \
        const float ru = (ratio_u1 < ratio_u2)                                \
            ? (uzfw * DD.uztwm - uztw * DD.uzfwm) * DD.r_uzsum : 0.f;         \
        const float euztw = fminf(ratio_u1 * Ep, uztw);                       \
        const float twexu = (uztw >= DD.uztwm) ? peff : 0.f;                  \
        const float qsur  = (uzfw >= DD.uzfwm) ? twexu : 0.f;                 \
        const float qint  = DD.kuz * uzfw;                                    \
        const float erem  = fmaxf(Ep - euztw, 0.f);                           \
        const float euzfw = fminf(uzfw, erem);                                \
        const float deficit = fmaxf(DD.lztwm - lztw, 0.f)                     \
            + fmaxf(DD.lzfwpm - lzfwp, 0.f) + fmaxf(DD.lzfwsm - lzfws, 0.f);  \
        const float powv = exp2f(DD.rexp1 * __log2f(deficit) - DD.c_pow);     \
        const float demand = DD.pbase + DD.Zp * powv;                         \
        const float srel = fmaxf(1e-8f, ratio_u2);                            \
        const float pc   = fmaxf(1e-8f, fminf(uzfw, srel * demand));          \
        const float pcfw = DD.pfree * pc;                                     \
        const float pctw = pc - pcfw;                                         \
        const float n1 = (DD.lzfwpm - lzfwp) * DD.lzfwsm;                     \
        const float n2 = (DD.lzfwsm - lzfws) * DD.lzfwpm;                     \
        const float ns = n1 + n2;                                             \
        const float flz = (ns != 0.f) ? n1 * rcpf(ns) : DD.flz_fb;            \
        const float pcfwp = flz * pcfw;                                       \
        const float pcfws = pcfw - pcfwp;                                     \
        const float lsum = lzfwp + lzfws;                                     \
        const float ratio_l = lztw * DD.r_lztwm;                              \
        const bool  lmask = lztw * DD.s23m < lsum * DD.lztwm;                 \
        const float nume = (lztw * DD.s23m + DD.lztwm * lsum) * DD.r_den;     \
        const float rlp = lmask ? lzfwp * nume : 0.f;                         \
        const float rls = lmask ? lzfws * nume : 0.f;                         \
        const float elztw = fminf(ratio_l * fmaxf(erem - euzfw, 0.f), lztw);  \
        const float twexl = (lztw >= DD.lztwm) ? pctw : 0.f;                  \
        const float twexlp = flz * twexl;                                     \
        const float twexls = twexl - twexlp;                                  \
        const float qbfp = DD.klzp * lzfwp;                                   \
        const float qbfs = DD.klzs * lzfws;                                   \
        QREG = qdir + qsur + qint + qbfp + qbfs;                              \
        uztw  = clampf(uztw + peff + ru - euztw - twexu, kPrecs, DD.uztwm);   \
        uzfw  = clampf(uzfw + twexu - ru - euzfw - qint - qsur - pc,          \
                       kPrecs, DD.uzfwm);                                     \
        lztw  = clampf(lztw + pctw - twexl + rlp + rls - elztw,               \
                       kPrecs, DD.lztwm);                                     \
        lzfwp = clampf(lzfwp + pcfwp + twexlp - rlp - qbfp, kPrecs, DD.lzfwpm); \
        lzfws = clampf(lzfws + pcfws + twexls - rls - qbfs, kPrecs, DD.lzfwsm); \
    } while (0)

    // body: FLUX with DCUR, build DNXT from BUF (t+1 params), rotate P/Ep, reissue BUF <- t+5
#define BODY(T, DCUR, DNXT, BUF, QREG) do {                                   \
        FLUX(DCUR, QREG);                                                     \
        DNXT = make_derived(BUF.pr);                                          \
        P = BUF.P; Ep = BUF.Ep;                                               \
        ISSUE(BUF, (T) + 5);   /* main loop: (T)+5 <= 364 always valid */     \
    } while (0)

    // tail body: no reissue
#define BODY_NR(DCUR, DNXT, BUF, QREG) do {                                   \
        FLUX(DCUR, QREG);                                                     \
        DNXT = make_derived(BUF.pr);                                          \
        P = BUF.P; Ep = BUF.Ep;                                               \
    } while (0)

    // batched m-reduction + store of 4 steps: xor1/xor2 via DPP, xor4 via swizzle
#define FLUSH(TB) do {                                                        \
        q0 = dpp_xadd<0xB1>(q0); q1 = dpp_xadd<0xB1>(q1);                     \
        q2 = dpp_xadd<0xB1>(q2); q3 = dpp_xadd<0xB1>(q3);                     \
        q0 = dpp_xadd<0x4E>(q0); q1 = dpp_xadd<0x4E>(q1);                     \
        q2 = dpp_xadd<0x4E>(q2); q3 = dpp_xadd<0x4E>(q3);                     \
        q0 += __shfl_xor(q0, 4); q1 += __shfl_xor(q1, 4);                     \
        q2 += __shfl_xor(q2, 4); q3 += __shfl_xor(q3, 4);                     \
        const float _v01 = (m & 1) ? q1 : q0;                                 \
        const float _v23 = (m & 1) ? q3 : q2;                                 \
        const float _v = (m & 2) ? _v23 : _v01;                               \
        if (m < 4) qs[(size_t)((TB) + m) * kG + g] = _v;                      \
    } while (0)

    for (int t = 0; t < 360; t += 4) {   // bodies 0..359; reissues reach t=364 max
        BODY(t,     d0, d1, A, q0);
        BODY(t + 1, d1, d0, B, q1);
        BODY(t + 2, d0, d1, C, q2);
        BODY(t + 3, d1, d0, D, q3);
        FLUSH(t);
    }
    // tail: bodies 360..364; buffers hold A:361 B:362 C:363 D:364
    BODY_NR(d0, d1, A, q0);
    BODY_NR(d1, d0, B, q1);
    BODY_NR(d0, d1, C, q2);
    BODY_NR(d1, d0, D, q3);
    FLUSH(360);
    FLUX(d0, q0);   // t=364 (even -> d0)
    q0 = dpp_xadd<0xB1>(q0);
    q0 = dpp_xadd<0x4E>(q0);
    q0 += __shfl_xor(q0, 4);
    if (m == 0) qs[(size_t)364 * kG + g] = q0;

#undef FLUX
#undef BODY
#undef BODY_NR
#undef ISSUE
#undef FLUSH
}

// ---------------- kernel B: gamma UH weights + pad zeroing (fused) ----------------
__global__ void uh_weights(const float* __restrict__ conv_params,
                           float* __restrict__ ws)   // scratch base
{
    const int idx = blockIdx.x * blockDim.x + threadIdx.x;
    if (idx < kQBase) ws[idx] = 0.f;          // zero the t<0 conv pad (every call)
    const int g = idx;
    if (g >= kG) return;
    float* wbuf = ws + kWBase;
    const float aa = fmaxf(conv_params[2 * g] * 2.9f, 0.f) + 0.1f;
    const float th = fmaxf(conv_params[2 * g + 1] * 6.5f, 0.f) + 0.5f;
    const float cw = expf(-lgammaf(aa)) * powf(th, -aa);
    float w[kF];
    float s = 0.f;
#pragma unroll
    for (int k = 0; k < kF; ++k) {
        const float tt = (float)k + 0.5f;
        w[k] = cw * powf(tt, aa - 1.f) * expf(-tt / th);
        s += w[k];
    }
    const float inv = 0.125f / s;   // normalize + fold ensemble mean (q stored as sum)
#pragma unroll
    for (int k = 0; k < kF; ++k) wbuf[k * kG + g] = w[k] * inv;
}

// ---------------- kernel C: causal UH convolution ----------------
__global__ void uh_conv(const float* __restrict__ ws,   // base of scratch
                        float* __restrict__ out)        // [T][G]
{
    const int tid = blockIdx.x * blockDim.x + threadIdx.x;
    if (tid >= kT * kG) return;
    const int t = tid / kG;
    const int g = tid - t * kG;
    const float* q = ws + kQBase;   // q[t] at q[t*kG+g]; t<0 hits the zero pad
    const float* w = ws + kWBase;
    float y = 0.f;
#pragma unroll
    for (int k = 0; k < kF; ++k)
        y += w[k * kG + g] * q[(ptrdiff_t)(t - k) * kG + g];
    out[(size_t)t * kG + g] = y;
}

}  // namespace

extern "C" void kernel_launch(void* const* d_in, const int* in_sizes, int n_in,
                              void* d_out, int out_size, void* d_ws, size_t ws_size,
                              hipStream_t stream) {
    const float* x           = (const float*)d_in[0];
    // d_in[1] = c_hydro_model — unused by the reference forward
    const float* params_raw  = (const float*)d_in[2];
    const float* conv_params = (const float*)d_in[3];
    float* out = (float*)d_out;
    float* ws  = (float*)d_ws;

    // fused: zero conv pad + compute UH weights (covers kQBase=30000 threads)
    uh_weights<<<(kQBase + 255) / 256, 256, 0, stream>>>(conv_params, ws);
    sacsma_scan<<<(kG * kM) / 64, 64, 0, stream>>>(x, params_raw, ws + kQBase);
    uh_conv<<<(kT * kG + 255) / 256, 256, 0, stream>>>(ws, out);
}